// Round 1
// baseline (155.952 us; speedup 1.0000x reference)
//
#include <hip/hip_runtime.h>
#include <hip/hip_bf16.h>

// Problem constants (N=2, C=256, H=W=64) — float32 I/O per reference.
#define NBATCH 2
#define CCH    256
#define LLEN   4096      // H*W
#define NGROUP 8
#define CPG    32        // C / NGROUP
#define NHEAD  4
#define HD     64        // C / NHEAD
#define GEPS   1e-5f
// q pre-scale: hd^-0.5 * log2(e); scores feed v_exp_f32 (2^x) directly.
#define QSCALE 0.18033688011112042f

// Generic MFMA fragment tiling (for 16x16x32 bf16): a [R x 256ch] tensor is
// stored as tiles [r16][c32] of 512 ushorts; element (r, c) sits at
// tile*512 + ((r&15) + 16*((c>>3)&3))*8 + (c&7).

typedef short bf16x8 __attribute__((ext_vector_type(8)));
typedef float f32x4  __attribute__((ext_vector_type(4)));

__device__ __forceinline__ unsigned short f2b(float f) {
  unsigned u = __float_as_uint(f);
  u += 0x7FFFu + ((u >> 16) & 1u);
  return (unsigned short)(u >> 16);
}
__device__ __forceinline__ unsigned pack2bf(float a, float b) {
  __hip_bfloat162 h = __float22bfloat162_rn(make_float2(a, b));
  union { __hip_bfloat162 h; unsigned u; } c;
  c.h = h;
  return c.u;
}
__device__ __forceinline__ float exp2_(float x) {
#if __has_builtin(__builtin_amdgcn_exp2f)
  return __builtin_amdgcn_exp2f(x);
#else
  return exp2f(x);
#endif
}

// ------- setup: wcvt->tiled W (blocks 0..255) | gn partials (256..511) | mask (512..543) -------
__global__ __launch_bounds__(256) void setup_kernel(
    const float* __restrict__ qw, const float* __restrict__ kw,
    const float* __restrict__ vw, const float* __restrict__ pw,
    const float* __restrict__ qb, const float* __restrict__ kb,
    const float* __restrict__ vb, const float* __restrict__ pb,
    const float* __restrict__ x, const int* __restrict__ mask,
    unsigned short* __restrict__ w16, float* __restrict__ bias_ws,
    float* __restrict__ part, float* __restrict__ out2) {
  __shared__ float rs[4], rss[4];
  const int b = blockIdx.x;
  const int t = threadIdx.x;
  if (b < 256) {
    const int idx = b * 256 + t;               // float4 units; 65536 total
    const int m = idx >> 14;
    const int rem = idx & 16383;
    const int cout = rem >> 6;                 // 0..255
    const int ch4 = (rem & 63) << 2;           // 0..252
    const float* src[4] = {qw, kw, vw, pw};
    const float sc = (m == 0) ? QSCALE : 1.0f;
    const float4 v = ((const float4*)src[m])[(size_t)cout * 64 + (ch4 >> 2)];
    // tiled store: [(m*16 + cout>>4)*8 + ch>>5]*512 + lane'*8 + ch&7
    unsigned short* dst = w16 +
        ((size_t)(m * 16 + (cout >> 4)) * 8 + (ch4 >> 5)) * 512 +
        ((cout & 15) + 16 * ((ch4 >> 3) & 3)) * 8 + (ch4 & 7);
    dst[0] = f2b(v.x * sc); dst[1] = f2b(v.y * sc);
    dst[2] = f2b(v.z * sc); dst[3] = f2b(v.w * sc);
    if (b == 0) {
      bias_ws[t]       = qb[t] * QSCALE;
      bias_ws[256 + t] = kb[t];
      bias_ws[512 + t] = vb[t];
      bias_ws[768 + t] = pb[t];
    }
  } else if (b < 512) {
    // GN partials: 256 blocks, 16 per group (was 8 — half the GPU sat idle).
    const int sb = b - 256;
    const int gidx = sb >> 4, sub = sb & 15;
    const float4* xp = (const float4*)(x + (size_t)gidx * (CPG * LLEN)) + (size_t)sub * 2048;
    float s = 0.f, ss = 0.f;
    for (int i = t; i < 2048; i += 256) {
      const float4 v = xp[i];
      s += v.x + v.y + v.z + v.w;
      ss = fmaf(v.x, v.x, ss);
      ss = fmaf(v.y, v.y, ss);
      ss = fmaf(v.z, v.z, ss);
      ss = fmaf(v.w, v.w, ss);
    }
#pragma unroll
    for (int off = 32; off; off >>= 1) {
      s  += __shfl_down(s, off);
      ss += __shfl_down(ss, off);
    }
    if ((t & 63) == 0) { rs[t >> 6] = s; rss[t >> 6] = ss; }
    __syncthreads();
    if (t == 0) {
      part[sb * 2 + 0] = rs[0] + rs[1] + rs[2] + rs[3];
      part[sb * 2 + 1] = rss[0] + rss[1] + rss[2] + rss[3];
    }
  } else {
    const int i = (b - 512) * 256 + t;
    out2[i] = (float)mask[i];
  }
}

// ------- GroupNorm apply + transpose -> bf16 xn, fragment-tiled.
//   Vectorized: float4 global loads along l, LDS transpose (pad 68 -> bank-
//   conflict-free), bf16x8 16B coalesced tiled stores. -------
__global__ __launch_bounds__(256) void gn_apply_kernel(const float* __restrict__ x,
                                                       const float* __restrict__ w,
                                                       const float* __restrict__ b,
                                                       const float* __restrict__ part,
                                                       unsigned short* __restrict__ xn16) {
  const int l0 = blockIdx.x * 64, c0 = blockIdx.y * 32, n = blockIdx.z;
  const int g16 = n * 8 + blockIdx.y;
  float s = 0.f, ss = 0.f;
#pragma unroll
  for (int i = 0; i < 16; i++) {
    s  += part[(g16 * 16 + i) * 2 + 0];
    ss += part[(g16 * 16 + i) * 2 + 1];
  }
  const float inv_cnt = 1.0f / (float)(CPG * LLEN);
  const float mu = s * inv_cnt;
  const float rsg = rsqrtf(ss * inv_cnt - mu * mu + GEPS);
  __shared__ float tile[32][68];   // pad 68: (c+l) mod 32 banks on reads
  const int t = threadIdx.x;
  const int cl = t >> 3, l8 = t & 7;
  const float aa = rsg * w[c0 + cl];
  const float dd = b[c0 + cl] - mu * aa;
  const float* xrow = x + ((size_t)n * CCH + c0 + cl) * LLEN + l0;
#pragma unroll
  for (int i = 0; i < 2; i++) {
    const int ll = (l8 + 8 * i) * 4;
    float4 v = *(const float4*)(xrow + ll);
    v.x = fmaf(v.x, aa, dd);
    v.y = fmaf(v.y, aa, dd);
    v.z = fmaf(v.z, aa, dd);
    v.w = fmaf(v.w, aa, dd);
    *(float4*)&tile[cl][ll] = v;
  }
  __syncthreads();
  const int l = t & 63, cg = t >> 6;      // each wave owns one 8-channel group
  const int labs = l0 + l;
  bf16x8 ov;
#pragma unroll
  for (int j = 0; j < 8; j++) ov[j] = (short)f2b(tile[cg * 8 + j][l]);
  const size_t pos = (((size_t)n * 256 + (labs >> 4)) * 8 + (c0 >> 5)) * 512 +
                     ((labs & 15) + 16 * cg) * 8;
  *(bf16x8*)(xn16 + pos) = ov;
}

// ------- QKV GEMM, LDS-free register MFMA. Block = 64 rows x 64 couts. -------
__global__ __launch_bounds__(256, 4) void qkv_mfma_kernel(
    const unsigned short* __restrict__ xn16,
    const unsigned short* __restrict__ w16,
    const float* __restrict__ bias_ws,
    unsigned short* __restrict__ q16,
    unsigned short* __restrict__ k16,
    unsigned short* __restrict__ v16) {
  const int t = threadIdx.x;
  const int lane = t & 63, wv = t >> 6;
  const int col = lane & 15, quad = lane >> 4;
  const int m0 = blockIdx.x * 64;
  const int by = blockIdx.y;                 // cout block (64)
  const int co0 = by * 64;
  const int wsel = blockIdx.z;
  const int n = m0 >> 12;
  const int m16b = (m0 & 4095) >> 4;

  const unsigned short* xnb = xn16 + (size_t)n * (256 * 8 * 512);
  const unsigned short* wb  = w16 + ((size_t)(wsel * 16 + by * 4 + wv) * 8) * 512 + lane * 8;

  f32x4 acc[4];
#pragma unroll
  for (int i = 0; i < 4; i++) acc[i] = {0.f, 0.f, 0.f, 0.f};

#pragma unroll
  for (int kc = 0; kc < 8; kc++) {
    const bf16x8 wf = *(const bf16x8*)(wb + (size_t)kc * 512);
#pragma unroll
    for (int mt = 0; mt < 4; mt++) {
      const bf16x8 xf = *(const bf16x8*)(xnb + ((size_t)(m16b + mt) * 8 + kc) * 512 + lane * 8);
      acc[mt] = (wsel < 2)
          ? __builtin_amdgcn_mfma_f32_16x16x32_bf16(xf, wf, acc[mt], 0, 0, 0)   // D[row][cout]
          : __builtin_amdgcn_mfma_f32_16x16x32_bf16(wf, xf, acc[mt], 0, 0, 0);  // D[cout][l]
    }
  }

  if (wsel < 2) {
    unsigned short* dst = (wsel == 0) ? q16 : k16;
    const float bias = bias_ws[wsel * CCH + co0 + wv * 16 + col];
    const int lquad = (wv * 2 + (col >> 3)) & 3;
    const int j = col & 7;
#pragma unroll
    for (int mt = 0; mt < 4; mt++) {
      const size_t base = ((size_t)(n * 256 + m16b + mt) * 8 + by * 2 + (wv >> 1)) * 512 + j;
#pragma unroll
      for (int r = 0; r < 4; r++)
        dst[base + ((quad * 4 + r) + 16 * lquad) * 8] = f2b(acc[mt][r] + bias);
    }
  } else {
    const int l0 = m0 & 4095;
    const int j = col & 7;
#pragma unroll
    for (int ct = 0; ct < 4; ct++) {
      const size_t base = ((size_t)(n * 128 + (l0 >> 5) + (ct >> 1)) * 16 + by * 4 + wv) * 512 +
                          16 * (((ct & 1) << 1) + (col >> 3)) * 8 + j;
#pragma unroll
      for (int r = 0; r < 4; r++) {
        const int cout = co0 + wv * 16 + quad * 4 + r;
        v16[base + (quad * 4 + r) * 8] = f2b(acc[ct][r] + bias_ws[2 * CCH + cout]);
      }
    }
  }
}

// ------- Flash attention v5: 32 q-rows/block (acc regs halved: ~120 total
//   incl. AGPRs -> 4 waves/SIMD instead of 2), 4 waves x 1024-key slices,
//   K ping-pong regs (no copy moves), V single-buffer top-loaded (latency
//   hides under QK^T), XCD-swizzled so each XCD L2 holds one head's K/V. -------
__global__ __launch_bounds__(256, 4) void attn_mfma_kernel(
    const unsigned short* __restrict__ q16,   // Q' tiled, pre-scaled
    const unsigned short* __restrict__ k16,   // K' tiled
    const unsigned short* __restrict__ v16,   // V' tiled
    unsigned short* __restrict__ o16) {       // O' tiled (normalized)
  __shared__ __align__(16) unsigned char shraw[20480];
  unsigned short (*pT)[32][40] = (unsigned short (*)[32][40])shraw;   // [wv][qrow][key+pad]
  f32x4 (*red)[4][64] = (f32x4 (*)[4][64])shraw;                      // [srcwv][ct][lane] 16KB
  f32x4 (*lred)[64] = (f32x4 (*)[64])(shraw + 16384);                 // [srcwv][lane] 4KB
  const int t = threadIdx.x;
  const int lane = t & 63, wv = t >> 6;
  const int col = lane & 15, quad = lane >> 4;
  // Bijective XCD swizzle (1024 blocks % 8 == 0): head = fid&7 -> one head
  // per XCD, its 1MB K/V resident in that XCD's private 4MB L2.
  const int fid = blockIdx.y * gridDim.x + blockIdx.x;
  const int nh = fid & 7, qx = fid >> 3;
  const int n = nh >> 2, h = nh & 3;
  const int hc = h * HD;
  const int qt0 = qx * 2;                     // base q16-tile (2 tiles = 32 rows)

  const unsigned short* qb = q16 + (size_t)n * (256 * 8 * 512);
  const unsigned short* kb = k16 + (size_t)n * (256 * 8 * 512);
  const unsigned short* vb = v16 + (size_t)n * (128 * 16 * 512);

  // Q B-frags (shared by all waves)
  bf16x8 bq[2][2];
#pragma unroll
  for (int qt = 0; qt < 2; qt++)
#pragma unroll
    for (int ks = 0; ks < 2; ks++)
      bq[qt][ks] = *(const bf16x8*)(qb + ((size_t)(qt0 + qt) * 8 + h * 2 + ks) * 512 + lane * 8);

  bf16x8 bones;
#pragma unroll
  for (int i = 0; i < 8; i++) bones[i] = (short)0x3F80;   // bf16 1.0

  f32x4 o[2][4], lacc[2];
#pragma unroll
  for (int qt = 0; qt < 2; qt++) {
    lacc[qt] = {0.f, 0.f, 0.f, 0.f};
#pragma unroll
    for (int ct = 0; ct < 4; ct++) o[qt][ct] = {0.f, 0.f, 0.f, 0.f};
  }

  auto ldK = [&](int kc0, int kt, int ks) {
    return *(const bf16x8*)(kb + ((size_t)((kc0 >> 4) + kt) * 8 + h * 2 + ks) * 512 + lane * 8);
  };
  auto ldV = [&](int kc0, int ct) {
    return *(const bf16x8*)(vb + ((size_t)(kc0 >> 5) * 16 + h * 4 + ct) * 512 + lane * 8);
  };

  bf16x8 kA[2][2], kB[2][2], bv[4];
  auto loadK = [&](bf16x8 (&kr)[2][2], int kc0) {
#pragma unroll
    for (int kt = 0; kt < 2; kt++)
#pragma unroll
      for (int ks = 0; ks < 2; ks++) kr[kt][ks] = ldK(kc0, kt, ks);
  };
  auto loadV = [&](int kc0) {
#pragma unroll
    for (int ct = 0; ct < 4; ct++) bv[ct] = ldV(kc0, ct);
  };
  auto chunk = [&](bf16x8 (&kr)[2][2]) {
    // S^T = K·Q^T; p = 2^s; pack to wave-private pT
#pragma unroll
    for (int kt = 0; kt < 2; kt++)
#pragma unroll
      for (int qt = 0; qt < 2; qt++) {
        f32x4 s = {0.f, 0.f, 0.f, 0.f};
        s = __builtin_amdgcn_mfma_f32_16x16x32_bf16(kr[kt][0], bq[qt][0], s, 0, 0, 0);
        s = __builtin_amdgcn_mfma_f32_16x16x32_bf16(kr[kt][1], bq[qt][1], s, 0, 0, 0);
        uint2 pw;
        pw.x = pack2bf(exp2_(s[0]), exp2_(s[1]));
        pw.y = pack2bf(exp2_(s[2]), exp2_(s[3]));
        *(uint2*)&pT[wv][qt * 16 + col][kt * 16 + quad * 4] = pw;
      }
    // PV + denominators
#pragma unroll
    for (int qt = 0; qt < 2; qt++) {
      const bf16x8 pa = *(const bf16x8*)&pT[wv][qt * 16 + col][quad * 8];
      lacc[qt] = __builtin_amdgcn_mfma_f32_16x16x32_bf16(pa, bones, lacc[qt], 0, 0, 0);
#pragma unroll
      for (int ct = 0; ct < 4; ct++)
        o[qt][ct] = __builtin_amdgcn_mfma_f32_16x16x32_bf16(pa, bv[ct], o[qt][ct], 0, 0, 0);
    }
  };

  const int kb0 = wv * 1024;                 // this wave's private key slice
  loadK(kA, kb0);
  for (int it = 0; it < 32; it += 2) {
    loadV(kb0 + it * 32);                    // V(it): latency hides under QK^T(it)
    loadK(kB, kb0 + (it + 1) * 32);          // it+1 <= 31, always valid
    chunk(kA);
    loadV(kb0 + (it + 1) * 32);
    loadK(kA, kb0 + ((it + 2 < 32) ? (it + 2) * 32 : (it + 1) * 32));
    chunk(kB);
  }

  // ---- merge across 4 waves, normalize, store O' tiled ----
  const int cch = hc + wv * 16 + col;        // channel this thread stores
  const int lquad16 = 16 * ((cch >> 3) & 3);
  const size_t ctile = cch >> 5;
#pragma unroll
  for (int qt = 0; qt < 2; qt++) {
    __syncthreads();
#pragma unroll
    for (int ct = 0; ct < 4; ct++) red[wv][ct][lane] = o[qt][ct];
    lred[wv][lane] = lacc[qt];
    __syncthreads();
    f32x4 os = red[0][wv][lane];
    os += red[1][wv][lane];
    os += red[2][wv][lane];
    os += red[3][wv][lane];
    f32x4 ls = lred[0][lane];
    ls += lred[1][lane];
    ls += lred[2][lane];
    ls += lred[3][lane];
    const size_t base = (((size_t)n * 256 + qt0 + qt) * 8 + ctile) * 512 + (cch & 7);
#pragma unroll
    for (int r = 0; r < 4; r++)
      o16[base + ((quad * 4 + r) + lquad16) * 8] = f2b(os[r] / ls[r]);
  }
}

// ------- Proj GEMM, 32-row M-tiles (1024 blocks -> 4 waves/SIMD), register
//   MFMA + bias + residual -> fp32 out [n,c,l] -------
__global__ __launch_bounds__(256, 4) void proj_mfma_kernel(
    const unsigned short* __restrict__ o16,     // O' tiled
    const unsigned short* __restrict__ w16,     // tiled weights (pw at tile 48)
    const float* __restrict__ pbias,
    const float* __restrict__ x,
    float* __restrict__ out) {
  const int t = threadIdx.x;
  const int lane = t & 63, wv = t >> 6;
  const int col = lane & 15, quad = lane >> 4;
  const int m0 = blockIdx.x * 32;            // l rows
  const int by = blockIdx.y;
  const int co0 = by * 64;
  const int n = m0 >> 12, l0 = m0 & 4095;

  const unsigned short* ob = o16 + (size_t)n * (256 * 8 * 512);
  const unsigned short* wb = w16 + ((size_t)(48 + by * 4 + wv) * 8) * 512 + lane * 8;

  f32x4 acc[2];
#pragma unroll
  for (int i = 0; i < 2; i++) acc[i] = {0.f, 0.f, 0.f, 0.f};

#pragma unroll
  for (int kc = 0; kc < 8; kc++) {
    const bf16x8 aw = *(const bf16x8*)(wb + (size_t)kc * 512);
#pragma unroll
    for (int lt = 0; lt < 2; lt++) {
      const bf16x8 bo = *(const bf16x8*)(ob + ((size_t)((l0 >> 4) + lt) * 8 + kc) * 512 + lane * 8);
      acc[lt] = __builtin_amdgcn_mfma_f32_16x16x32_bf16(aw, bo, acc[lt], 0, 0, 0);  // D[cout][l]
    }
  }
#pragma unroll
  for (int lt = 0; lt < 2; lt++)
#pragma unroll
    for (int r = 0; r < 4; r++) {
      const int cout = co0 + wv * 16 + quad * 4 + r;
      const size_t idx = ((size_t)(n * CCH + cout)) * LLEN + l0 + lt * 16 + col;
      out[idx] = acc[lt][r] + pbias[cout] + x[idx];
    }
}

extern "C" void kernel_launch(void* const* d_in, const int* in_sizes, int n_in,
                              void* d_out, int out_size, void* d_ws, size_t ws_size,
                              hipStream_t stream) {
  (void)in_sizes; (void)n_in; (void)out_size; (void)ws_size;
  const float* x      = (const float*)d_in[0];
  const int*   mask   = (const int*)d_in[1];
  const float* norm_w = (const float*)d_in[2];
  const float* norm_b = (const float*)d_in[3];
  const float* q_w    = (const float*)d_in[4];
  const float* q_b    = (const float*)d_in[5];
  const float* k_w    = (const float*)d_in[6];
  const float* k_b    = (const float*)d_in[7];
  const float* v_w    = (const float*)d_in[8];
  const float* v_b    = (const float*)d_in[9];
  const float* p_w    = (const float*)d_in[10];
  const float* p_b    = (const float*)d_in[11];

  const size_t TSZ = (size_t)NBATCH * LLEN * CCH;   // 2097152 elements
  unsigned short* xn16 = (unsigned short*)d_ws;     // TSZ (tiled)
  unsigned short* q16  = xn16 + TSZ;                // tiled
  unsigned short* k16  = q16 + TSZ;                 // tiled
  unsigned short* v16  = k16 + TSZ;                 // tiled
  unsigned short* o16  = v16 + TSZ;                 // tiled
  unsigned short* w16  = o16 + TSZ;                 // 4*65536 (tiled)
  float* bias_ws = (float*)(w16 + 4 * 65536);       // 4*256
  float* part    = bias_ws + 1024;                  // 512
  // total ~21 MB

  float* out  = (float*)d_out;
  float* out2 = out + TSZ;   // mask chunk

  setup_kernel<<<544, 256, 0, stream>>>(q_w, k_w, v_w, p_w, q_b, k_b, v_b, p_b,
                                        x, mask, w16, bias_ws, part, out2);
  gn_apply_kernel<<<dim3(LLEN / 64, CCH / 32, NBATCH), 256, 0, stream>>>(
      x, norm_w, norm_b, part, xn16);
  qkv_mfma_kernel<<<dim3((NBATCH * LLEN) / 64, CCH / 64, 3), 256, 0, stream>>>(
      xn16, w16, bias_ws, q16, k16, v16);
  attn_mfma_kernel<<<dim3(LLEN / 32, NBATCH * NHEAD), 256, 0, stream>>>(
      q16, k16, v16, o16);
  proj_mfma_kernel<<<dim3((NBATCH * LLEN) / 32, CCH / 64), 256, 0, stream>>>(
      o16, w16, bias_ws + 768, x, out);
}

// Round 2
// 148.460 us; speedup vs baseline: 1.0505x; 1.0505x over previous
//
#include <hip/hip_runtime.h>
#include <hip/hip_bf16.h>

// Problem constants (N=2, C=256, H=W=64) — float32 I/O per reference.
#define NBATCH 2
#define CCH    256
#define LLEN   4096      // H*W
#define NGROUP 8
#define CPG    32        // C / NGROUP
#define NHEAD  4
#define HD     64        // C / NHEAD
#define GEPS   1e-5f
// q pre-scale: hd^-0.5 * log2(e); scores feed v_exp_f32 (2^x) directly.
#define QSCALE 0.18033688011112042f

// Generic MFMA fragment tiling (for 16x16x32 bf16): a [R x 256ch] tensor is
// stored as tiles [r16][c32] of 512 ushorts; element (r, c) sits at
// tile*512 + ((r&15) + 16*((c>>3)&3))*8 + (c&7).

typedef short bf16x8 __attribute__((ext_vector_type(8)));
typedef float f32x4  __attribute__((ext_vector_type(4)));

__device__ __forceinline__ unsigned short f2b(float f) {
  unsigned u = __float_as_uint(f);
  u += 0x7FFFu + ((u >> 16) & 1u);
  return (unsigned short)(u >> 16);
}
__device__ __forceinline__ unsigned pack2bf(float a, float b) {
  __hip_bfloat162 h = __float22bfloat162_rn(make_float2(a, b));
  union { __hip_bfloat162 h; unsigned u; } c;
  c.h = h;
  return c.u;
}
__device__ __forceinline__ float exp2_(float x) {
#if __has_builtin(__builtin_amdgcn_exp2f)
  return __builtin_amdgcn_exp2f(x);
#else
  return exp2f(x);
#endif
}

// ------- setup: wcvt->tiled W (blocks 0..255) | gn partials (256..511) | mask (512..543) -------
__global__ __launch_bounds__(256) void setup_kernel(
    const float* __restrict__ qw, const float* __restrict__ kw,
    const float* __restrict__ vw, const float* __restrict__ pw,
    const float* __restrict__ qb, const float* __restrict__ kb,
    const float* __restrict__ vb, const float* __restrict__ pb,
    const float* __restrict__ x, const int* __restrict__ mask,
    unsigned short* __restrict__ w16, float* __restrict__ bias_ws,
    float* __restrict__ part, float* __restrict__ out2) {
  __shared__ float rs[4], rss[4];
  const int b = blockIdx.x;
  const int t = threadIdx.x;
  if (b < 256) {
    const int idx = b * 256 + t;               // float4 units; 65536 total
    const int m = idx >> 14;
    const int rem = idx & 16383;
    const int cout = rem >> 6;                 // 0..255
    const int ch4 = (rem & 63) << 2;           // 0..252
    const float* src[4] = {qw, kw, vw, pw};
    const float sc = (m == 0) ? QSCALE : 1.0f;
    const float4 v = ((const float4*)src[m])[(size_t)cout * 64 + (ch4 >> 2)];
    // tiled store: [(m*16 + cout>>4)*8 + ch>>5]*512 + lane'*8 + ch&7
    unsigned short* dst = w16 +
        ((size_t)(m * 16 + (cout >> 4)) * 8 + (ch4 >> 5)) * 512 +
        ((cout & 15) + 16 * ((ch4 >> 3) & 3)) * 8 + (ch4 & 7);
    dst[0] = f2b(v.x * sc); dst[1] = f2b(v.y * sc);
    dst[2] = f2b(v.z * sc); dst[3] = f2b(v.w * sc);
    if (b == 0) {
      bias_ws[t]       = qb[t] * QSCALE;
      bias_ws[256 + t] = kb[t];
      bias_ws[512 + t] = vb[t];
      bias_ws[768 + t] = pb[t];
    }
  } else if (b < 512) {
    // GN partials: 256 blocks, 16 per group.
    const int sb = b - 256;
    const int gidx = sb >> 4, sub = sb & 15;
    const float4* xp = (const float4*)(x + (size_t)gidx * (CPG * LLEN)) + (size_t)sub * 2048;
    float s = 0.f, ss = 0.f;
    for (int i = t; i < 2048; i += 256) {
      const float4 v = xp[i];
      s += v.x + v.y + v.z + v.w;
      ss = fmaf(v.x, v.x, ss);
      ss = fmaf(v.y, v.y, ss);
      ss = fmaf(v.z, v.z, ss);
      ss = fmaf(v.w, v.w, ss);
    }
#pragma unroll
    for (int off = 32; off; off >>= 1) {
      s  += __shfl_down(s, off);
      ss += __shfl_down(ss, off);
    }
    if ((t & 63) == 0) { rs[t >> 6] = s; rss[t >> 6] = ss; }
    __syncthreads();
    if (t == 0) {
      part[sb * 2 + 0] = rs[0] + rs[1] + rs[2] + rs[3];
      part[sb * 2 + 1] = rss[0] + rss[1] + rss[2] + rss[3];
    }
  } else {
    const int i = (b - 512) * 256 + t;
    out2[i] = (float)mask[i];
  }
}

// ------- GroupNorm apply + transpose -> bf16 xn, fragment-tiled.
//   Vectorized: float4 global loads along l, LDS transpose, bf16x8 stores. -------
__global__ __launch_bounds__(256) void gn_apply_kernel(const float* __restrict__ x,
                                                       const float* __restrict__ w,
                                                       const float* __restrict__ b,
                                                       const float* __restrict__ part,
                                                       unsigned short* __restrict__ xn16) {
  const int l0 = blockIdx.x * 64, c0 = blockIdx.y * 32, n = blockIdx.z;
  const int g16 = n * 8 + blockIdx.y;
  float s = 0.f, ss = 0.f;
#pragma unroll
  for (int i = 0; i < 16; i++) {
    s  += part[(g16 * 16 + i) * 2 + 0];
    ss += part[(g16 * 16 + i) * 2 + 1];
  }
  const float inv_cnt = 1.0f / (float)(CPG * LLEN);
  const float mu = s * inv_cnt;
  const float rsg = rsqrtf(ss * inv_cnt - mu * mu + GEPS);
  __shared__ float tile[32][68];
  const int t = threadIdx.x;
  const int cl = t >> 3, l8 = t & 7;
  const float aa = rsg * w[c0 + cl];
  const float dd = b[c0 + cl] - mu * aa;
  const float* xrow = x + ((size_t)n * CCH + c0 + cl) * LLEN + l0;
#pragma unroll
  for (int i = 0; i < 2; i++) {
    const int ll = (l8 + 8 * i) * 4;
    float4 v = *(const float4*)(xrow + ll);
    v.x = fmaf(v.x, aa, dd);
    v.y = fmaf(v.y, aa, dd);
    v.z = fmaf(v.z, aa, dd);
    v.w = fmaf(v.w, aa, dd);
    *(float4*)&tile[cl][ll] = v;
  }
  __syncthreads();
  const int l = t & 63, cg = t >> 6;      // each wave owns one 8-channel group
  const int labs = l0 + l;
  bf16x8 ov;
#pragma unroll
  for (int j = 0; j < 8; j++) ov[j] = (short)f2b(tile[cg * 8 + j][l]);
  const size_t pos = (((size_t)n * 256 + (labs >> 4)) * 8 + (c0 >> 5)) * 512 +
                     ((labs & 15) + 16 * cg) * 8;
  *(bf16x8*)(xn16 + pos) = ov;
}

// ------- QKV GEMM, LDS-free register MFMA. Block = 64 rows x 64 couts. -------
__global__ __launch_bounds__(256, 4) void qkv_mfma_kernel(
    const unsigned short* __restrict__ xn16,
    const unsigned short* __restrict__ w16,
    const float* __restrict__ bias_ws,
    unsigned short* __restrict__ q16,
    unsigned short* __restrict__ k16,
    unsigned short* __restrict__ v16) {
  const int t = threadIdx.x;
  const int lane = t & 63, wv = t >> 6;
  const int col = lane & 15, quad = lane >> 4;
  const int m0 = blockIdx.x * 64;
  const int by = blockIdx.y;                 // cout block (64)
  const int co0 = by * 64;
  const int wsel = blockIdx.z;
  const int n = m0 >> 12;
  const int m16b = (m0 & 4095) >> 4;

  const unsigned short* xnb = xn16 + (size_t)n * (256 * 8 * 512);
  const unsigned short* wb  = w16 + ((size_t)(wsel * 16 + by * 4 + wv) * 8) * 512 + lane * 8;

  f32x4 acc[4];
#pragma unroll
  for (int i = 0; i < 4; i++) acc[i] = {0.f, 0.f, 0.f, 0.f};

#pragma unroll
  for (int kc = 0; kc < 8; kc++) {
    const bf16x8 wf = *(const bf16x8*)(wb + (size_t)kc * 512);
#pragma unroll
    for (int mt = 0; mt < 4; mt++) {
      const bf16x8 xf = *(const bf16x8*)(xnb + ((size_t)(m16b + mt) * 8 + kc) * 512 + lane * 8);
      acc[mt] = (wsel < 2)
          ? __builtin_amdgcn_mfma_f32_16x16x32_bf16(xf, wf, acc[mt], 0, 0, 0)   // D[row][cout]
          : __builtin_amdgcn_mfma_f32_16x16x32_bf16(wf, xf, acc[mt], 0, 0, 0);  // D[cout][l]
    }
  }

  if (wsel < 2) {
    unsigned short* dst = (wsel == 0) ? q16 : k16;
    const float bias = bias_ws[wsel * CCH + co0 + wv * 16 + col];
    const int lquad = (wv * 2 + (col >> 3)) & 3;
    const int j = col & 7;
#pragma unroll
    for (int mt = 0; mt < 4; mt++) {
      const size_t base = ((size_t)(n * 256 + m16b + mt) * 8 + by * 2 + (wv >> 1)) * 512 + j;
#pragma unroll
      for (int r = 0; r < 4; r++)
        dst[base + ((quad * 4 + r) + 16 * lquad) * 8] = f2b(acc[mt][r] + bias);
    }
  } else {
    const int l0 = m0 & 4095;
    const int j = col & 7;
#pragma unroll
    for (int ct = 0; ct < 4; ct++) {
      const size_t base = ((size_t)(n * 128 + (l0 >> 5) + (ct >> 1)) * 16 + by * 4 + wv) * 512 +
                          16 * (((ct & 1) << 1) + (col >> 3)) * 8 + j;
#pragma unroll
      for (int r = 0; r < 4; r++) {
        const int cout = co0 + wv * 16 + quad * 4 + r;
        v16[base + (quad * 4 + r) * 8] = f2b(acc[ct][r] + bias_ws[2 * CCH + cout]);
      }
    }
  }
}

// ------- Flash attention v6: qt=4 (64 q-rows, best arith intensity), XCD
//   swizzle (keep: FETCH 35->6MB), K/V reg ping-pong, and IN-REGISTER P:
//   cvt_pk + permlane32/16_swap replaces the pT LDS round trip (no ds_write/
//   ds_read/lgkmcnt on critical path, 3.1M conflict cycles removed).
//   s_setprio(1) around pure-MFMA PV cluster (T5). 2 waves/SIMD. -------
__global__ __launch_bounds__(256, 2) void attn_mfma_kernel(
    const unsigned short* __restrict__ q16,   // Q' tiled, pre-scaled
    const unsigned short* __restrict__ k16,   // K' tiled
    const unsigned short* __restrict__ v16,   // V' tiled
    unsigned short* __restrict__ o16) {       // O' tiled (normalized)
  __shared__ __align__(16) unsigned char shraw[20480];
  f32x4 (*red)[4][64] = (f32x4 (*)[4][64])shraw;                      // [srcwv][ct][lane] 16KB
  f32x4 (*lred)[64] = (f32x4 (*)[64])(shraw + 16384);                 // [srcwv][lane] 4KB
  const int t = threadIdx.x;
  const int lane = t & 63, wv = t >> 6;
  const int col = lane & 15, quad = lane >> 4;
  // Bijective XCD swizzle (512 blocks % 8 == 0): head = fid&7 -> one head
  // per XCD, its 1MB K/V resident in that XCD's private 4MB L2.
  const int fid = blockIdx.y * gridDim.x + blockIdx.x;
  const int nh = fid & 7, qx = fid >> 3;
  const int n = nh >> 2, h = nh & 3;
  const int hc = h * HD;
  const int qt0 = qx * 4;                     // base q16-tile (4 tiles = 64 rows)

  const unsigned short* qb = q16 + (size_t)n * (256 * 8 * 512);
  const unsigned short* kb = k16 + (size_t)n * (256 * 8 * 512);
  const unsigned short* vb = v16 + (size_t)n * (128 * 16 * 512);

  // Q B-frags (shared by all waves)
  bf16x8 bq[4][2];
#pragma unroll
  for (int qt = 0; qt < 4; qt++)
#pragma unroll
    for (int ks = 0; ks < 2; ks++)
      bq[qt][ks] = *(const bf16x8*)(qb + ((size_t)(qt0 + qt) * 8 + h * 2 + ks) * 512 + lane * 8);

  bf16x8 bones;
#pragma unroll
  for (int i = 0; i < 8; i++) bones[i] = (short)0x3F80;   // bf16 1.0

  f32x4 o[4][4], lacc[4];
#pragma unroll
  for (int qt = 0; qt < 4; qt++) {
    lacc[qt] = {0.f, 0.f, 0.f, 0.f};
#pragma unroll
    for (int ct = 0; ct < 4; ct++) o[qt][ct] = {0.f, 0.f, 0.f, 0.f};
  }

  auto ldK = [&](int kc0, int kt, int ks) {
    return *(const bf16x8*)(kb + ((size_t)((kc0 >> 4) + kt) * 8 + h * 2 + ks) * 512 + lane * 8);
  };
  auto ldV = [&](int kc0, int ct) {
    return *(const bf16x8*)(vb + ((size_t)(kc0 >> 5) * 16 + h * 4 + ct) * 512 + lane * 8);
  };

  bf16x8 kA[2][2], kB[2][2], vA[4], vB[4];
  auto loadK = [&](bf16x8 (&kr)[2][2], int kc0) {
#pragma unroll
    for (int kt = 0; kt < 2; kt++)
#pragma unroll
      for (int ks = 0; ks < 2; ks++) kr[kt][ks] = ldK(kc0, kt, ks);
  };
  auto loadV = [&](bf16x8 (&vv)[4], int kc0) {
#pragma unroll
    for (int ct = 0; ct < 4; ct++) vv[ct] = ldV(kc0, ct);
  };

  auto chunk = [&](bf16x8 (&kr)[2][2], bf16x8 (&vv)[4]) {
    // S^T = K·Q^T; p = 2^s packed to bf16; permlane exchange -> PV A-frags.
    // Source: lane(col,quad p) kt-word a_j = keys kt*16+4p+{2j,2j+1}.
    // Target: lane(col,quad q') word w = keys 8q'+{2w,2w+1}.
    // (w0,w2) = pl16_swap(pl32_swap(a0,b0)); (w1,w3) likewise from (a1,b1).
    bf16x8 pa[4];
#pragma unroll
    for (int qt = 0; qt < 4; qt++) {
      unsigned a0, a1, b0, b1;
      {
        f32x4 s = {0.f, 0.f, 0.f, 0.f};
        s = __builtin_amdgcn_mfma_f32_16x16x32_bf16(kr[0][0], bq[qt][0], s, 0, 0, 0);
        s = __builtin_amdgcn_mfma_f32_16x16x32_bf16(kr[0][1], bq[qt][1], s, 0, 0, 0);
        a0 = pack2bf(exp2_(s[0]), exp2_(s[1]));
        a1 = pack2bf(exp2_(s[2]), exp2_(s[3]));
      }
      {
        f32x4 s = {0.f, 0.f, 0.f, 0.f};
        s = __builtin_amdgcn_mfma_f32_16x16x32_bf16(kr[1][0], bq[qt][0], s, 0, 0, 0);
        s = __builtin_amdgcn_mfma_f32_16x16x32_bf16(kr[1][1], bq[qt][1], s, 0, 0, 0);
        b0 = pack2bf(exp2_(s[0]), exp2_(s[1]));
        b1 = pack2bf(exp2_(s[2]), exp2_(s[3]));
      }
      auto r0 = __builtin_amdgcn_permlane32_swap(a0, b0, false, false);
      auto s0 = __builtin_amdgcn_permlane16_swap(r0[0], r0[1], false, false);
      auto r1 = __builtin_amdgcn_permlane32_swap(a1, b1, false, false);
      auto s1 = __builtin_amdgcn_permlane16_swap(r1[0], r1[1], false, false);
      union { unsigned u[4]; bf16x8 v; } pu;
      pu.u[0] = s0[0];   // w0 = keys 8q'+0,1
      pu.u[1] = s1[0];   // w1 = keys 8q'+2,3
      pu.u[2] = s0[1];   // w2 = keys 8q'+4,5
      pu.u[3] = s1[1];   // w3 = keys 8q'+6,7
      pa[qt] = pu.v;
    }
    // PV + denominators — pure MFMA cluster
    __builtin_amdgcn_s_setprio(1);
#pragma unroll
    for (int qt = 0; qt < 4; qt++) {
      lacc[qt] = __builtin_amdgcn_mfma_f32_16x16x32_bf16(pa[qt], bones, lacc[qt], 0, 0, 0);
#pragma unroll
      for (int ct = 0; ct < 4; ct++)
        o[qt][ct] = __builtin_amdgcn_mfma_f32_16x16x32_bf16(pa[qt], vv[ct], o[qt][ct], 0, 0, 0);
    }
    __builtin_amdgcn_s_setprio(0);
  };

  const int kb0 = wv * 1024;                 // this wave's private key slice
  loadK(kA, kb0);
  loadV(vA, kb0);
  for (int it = 0; it < 32; it += 2) {
    loadK(kB, kb0 + (it + 1) * 32);
    loadV(vB, kb0 + (it + 1) * 32);
    chunk(kA, vA);
    const int nx = (it + 2 < 32) ? (it + 2) : (it + 1);
    loadK(kA, kb0 + nx * 32);
    loadV(vA, kb0 + nx * 32);
    chunk(kB, vB);
  }

  // ---- merge across 4 waves, normalize, store O' tiled ----
  const int cch = hc + wv * 16 + col;        // channel this thread stores
  const int lquad16 = 16 * ((cch >> 3) & 3);
  const size_t ctile = cch >> 5;
#pragma unroll
  for (int qt = 0; qt < 4; qt++) {
    __syncthreads();
#pragma unroll
    for (int ct = 0; ct < 4; ct++) red[wv][ct][lane] = o[qt][ct];
    lred[wv][lane] = lacc[qt];
    __syncthreads();
    f32x4 os = red[0][wv][lane];
    os += red[1][wv][lane];
    os += red[2][wv][lane];
    os += red[3][wv][lane];
    f32x4 ls = lred[0][lane];
    ls += lred[1][lane];
    ls += lred[2][lane];
    ls += lred[3][lane];
    const size_t base = (((size_t)n * 256 + qt0 + qt) * 8 + ctile) * 512 + (cch & 7);
#pragma unroll
    for (int r = 0; r < 4; r++)
      o16[base + ((quad * 4 + r) + lquad16) * 8] = f2b(os[r] / ls[r]);
  }
}

// ------- Proj GEMM, 32-row M-tiles, register MFMA + bias + residual -> fp32 out -------
__global__ __launch_bounds__(256, 4) void proj_mfma_kernel(
    const unsigned short* __restrict__ o16,     // O' tiled
    const unsigned short* __restrict__ w16,     // tiled weights (pw at tile 48)
    const float* __restrict__ pbias,
    const float* __restrict__ x,
    float* __restrict__ out) {
  const int t = threadIdx.x;
  const int lane = t & 63, wv = t >> 6;
  const int col = lane & 15, quad = lane >> 4;
  const int m0 = blockIdx.x * 32;            // l rows
  const int by = blockIdx.y;
  const int co0 = by * 64;
  const int n = m0 >> 12, l0 = m0 & 4095;

  const unsigned short* ob = o16 + (size_t)n * (256 * 8 * 512);
  const unsigned short* wb = w16 + ((size_t)(48 + by * 4 + wv) * 8) * 512 + lane * 8;

  f32x4 acc[2];
#pragma unroll
  for (int i = 0; i < 2; i++) acc[i] = {0.f, 0.f, 0.f, 0.f};

#pragma unroll
  for (int kc = 0; kc < 8; kc++) {
    const bf16x8 aw = *(const bf16x8*)(wb + (size_t)kc * 512);
#pragma unroll
    for (int lt = 0; lt < 2; lt++) {
      const bf16x8 bo = *(const bf16x8*)(ob + ((size_t)((l0 >> 4) + lt) * 8 + kc) * 512 + lane * 8);
      acc[lt] = __builtin_amdgcn_mfma_f32_16x16x32_bf16(aw, bo, acc[lt], 0, 0, 0);  // D[cout][l]
    }
  }
#pragma unroll
  for (int lt = 0; lt < 2; lt++)
#pragma unroll
    for (int r = 0; r < 4; r++) {
      const int cout = co0 + wv * 16 + quad * 4 + r;
      const size_t idx = ((size_t)(n * CCH + cout)) * LLEN + l0 + lt * 16 + col;
      out[idx] = acc[lt][r] + pbias[cout] + x[idx];
    }
}

extern "C" void kernel_launch(void* const* d_in, const int* in_sizes, int n_in,
                              void* d_out, int out_size, void* d_ws, size_t ws_size,
                              hipStream_t stream) {
  (void)in_sizes; (void)n_in; (void)out_size; (void)ws_size;
  const float* x      = (const float*)d_in[0];
  const int*   mask   = (const int*)d_in[1];
  const float* norm_w = (const float*)d_in[2];
  const float* norm_b = (const float*)d_in[3];
  const float* q_w    = (const float*)d_in[4];
  const float* q_b    = (const float*)d_in[5];
  const float* k_w    = (const float*)d_in[6];
  const float* k_b    = (const float*)d_in[7];
  const float* v_w    = (const float*)d_in[8];
  const float* v_b    = (const float*)d_in[9];
  const float* p_w    = (const float*)d_in[10];
  const float* p_b    = (const float*)d_in[11];

  const size_t TSZ = (size_t)NBATCH * LLEN * CCH;   // 2097152 elements
  unsigned short* xn16 = (unsigned short*)d_ws;     // TSZ (tiled)
  unsigned short* q16  = xn16 + TSZ;                // tiled
  unsigned short* k16  = q16 + TSZ;                 // tiled
  unsigned short* v16  = k16 + TSZ;                 // tiled
  unsigned short* o16  = v16 + TSZ;                 // tiled
  unsigned short* w16  = o16 + TSZ;                 // 4*65536 (tiled)
  float* bias_ws = (float*)(w16 + 4 * 65536);       // 4*256
  float* part    = bias_ws + 1024;                  // 512
  // total ~21 MB

  float* out  = (float*)d_out;
  float* out2 = out + TSZ;   // mask chunk

  setup_kernel<<<544, 256, 0, stream>>>(q_w, k_w, v_w, p_w, q_b, k_b, v_b, p_b,
                                        x, mask, w16, bias_ws, part, out2);
  gn_apply_kernel<<<dim3(LLEN / 64, CCH / 32, NBATCH), 256, 0, stream>>>(
      x, norm_w, norm_b, part, xn16);
  qkv_mfma_kernel<<<dim3((NBATCH * LLEN) / 64, CCH / 64, 3), 256, 0, stream>>>(
      xn16, w16, bias_ws, q16, k16, v16);
  attn_mfma_kernel<<<dim3(LLEN / 64, NBATCH * NHEAD), 256, 0, stream>>>(
      q16, k16, v16, o16);
  proj_mfma_kernel<<<dim3((NBATCH * LLEN) / 32, CCH / 64), 256, 0, stream>>>(
      o16, w16, bias_ws + 768, x, out);
}

// Round 3
// 147.001 us; speedup vs baseline: 1.0609x; 1.0099x over previous
//
#include <hip/hip_runtime.h>
#include <hip/hip_bf16.h>

// Problem constants (N=2, C=256, H=W=64) — float32 I/O per reference.
#define NBATCH 2
#define CCH    256
#define LLEN   4096      // H*W
#define NGROUP 8
#define CPG    32        // C / NGROUP
#define NHEAD  4
#define HD     64        // C / NHEAD
#define GEPS   1e-5f
// q pre-scale: hd^-0.5 * log2(e); scores feed v_exp_f32 (2^x) directly.
#define QSCALE 0.18033688011112042f

// Generic MFMA fragment tiling (for 16x16x32 bf16): a [R x 256ch] tensor is
// stored as tiles [r16][c32] of 512 ushorts; element (r, c) sits at
// tile*512 + ((r&15) + 16*((c>>3)&3))*8 + (c&7).

typedef short bf16x8 __attribute__((ext_vector_type(8)));
typedef float f32x4  __attribute__((ext_vector_type(4)));

__device__ __forceinline__ unsigned short f2b(float f) {
  unsigned u = __float_as_uint(f);
  u += 0x7FFFu + ((u >> 16) & 1u);
  return (unsigned short)(u >> 16);
}
__device__ __forceinline__ unsigned pack2bf(float a, float b) {
  __hip_bfloat162 h = __float22bfloat162_rn(make_float2(a, b));
  union { __hip_bfloat162 h; unsigned u; } c;
  c.h = h;
  return c.u;
}
__device__ __forceinline__ float exp2_(float x) {
#if __has_builtin(__builtin_amdgcn_exp2f)
  return __builtin_amdgcn_exp2f(x);
#else
  return exp2f(x);
#endif
}

// ------- setup: wcvt->tiled W (blocks 0..255) | gn partials (256..511) | mask (512..543) -------
__global__ __launch_bounds__(256) void setup_kernel(
    const float* __restrict__ qw, const float* __restrict__ kw,
    const float* __restrict__ vw, const float* __restrict__ pw,
    const float* __restrict__ qb, const float* __restrict__ kb,
    const float* __restrict__ vb, const float* __restrict__ pb,
    const float* __restrict__ x, const int* __restrict__ mask,
    unsigned short* __restrict__ w16, float* __restrict__ bias_ws,
    float* __restrict__ part, float* __restrict__ out2) {
  __shared__ float rs[4], rss[4];
  const int b = blockIdx.x;
  const int t = threadIdx.x;
  if (b < 256) {
    const int idx = b * 256 + t;               // float4 units; 65536 total
    const int m = idx >> 14;
    const int rem = idx & 16383;
    const int cout = rem >> 6;                 // 0..255
    const int ch4 = (rem & 63) << 2;           // 0..252
    const float* src[4] = {qw, kw, vw, pw};
    const float sc = (m == 0) ? QSCALE : 1.0f;
    const float4 v = ((const float4*)src[m])[(size_t)cout * 64 + (ch4 >> 2)];
    // tiled store: [(m*16 + cout>>4)*8 + ch>>5]*512 + lane'*8 + ch&7
    unsigned short* dst = w16 +
        ((size_t)(m * 16 + (cout >> 4)) * 8 + (ch4 >> 5)) * 512 +
        ((cout & 15) + 16 * ((ch4 >> 3) & 3)) * 8 + (ch4 & 7);
    dst[0] = f2b(v.x * sc); dst[1] = f2b(v.y * sc);
    dst[2] = f2b(v.z * sc); dst[3] = f2b(v.w * sc);
    if (b == 0) {
      bias_ws[t]       = qb[t] * QSCALE;
      bias_ws[256 + t] = kb[t];
      bias_ws[512 + t] = vb[t];
      bias_ws[768 + t] = pb[t];
    }
  } else if (b < 512) {
    // GN partials: 256 blocks, 16 per group.
    const int sb = b - 256;
    const int gidx = sb >> 4, sub = sb & 15;
    const float4* xp = (const float4*)(x + (size_t)gidx * (CPG * LLEN)) + (size_t)sub * 2048;
    float s = 0.f, ss = 0.f;
    for (int i = t; i < 2048; i += 256) {
      const float4 v = xp[i];
      s += v.x + v.y + v.z + v.w;
      ss = fmaf(v.x, v.x, ss);
      ss = fmaf(v.y, v.y, ss);
      ss = fmaf(v.z, v.z, ss);
      ss = fmaf(v.w, v.w, ss);
    }
#pragma unroll
    for (int off = 32; off; off >>= 1) {
      s  += __shfl_down(s, off);
      ss += __shfl_down(ss, off);
    }
    if ((t & 63) == 0) { rs[t >> 6] = s; rss[t >> 6] = ss; }
    __syncthreads();
    if (t == 0) {
      part[sb * 2 + 0] = rs[0] + rs[1] + rs[2] + rs[3];
      part[sb * 2 + 1] = rss[0] + rss[1] + rss[2] + rss[3];
    }
  } else {
    const int i = (b - 512) * 256 + t;
    out2[i] = (float)mask[i];
  }
}

// ------- GroupNorm apply + transpose -> bf16 xn, fragment-tiled.
//   Vectorized: float4 global loads along l, LDS transpose, bf16x8 stores. -------
__global__ __launch_bounds__(256) void gn_apply_kernel(const float* __restrict__ x,
                                                       const float* __restrict__ w,
                                                       const float* __restrict__ b,
                                                       const float* __restrict__ part,
                                                       unsigned short* __restrict__ xn16) {
  const int l0 = blockIdx.x * 64, c0 = blockIdx.y * 32, n = blockIdx.z;
  const int g16 = n * 8 + blockIdx.y;
  float s = 0.f, ss = 0.f;
#pragma unroll
  for (int i = 0; i < 16; i++) {
    s  += part[(g16 * 16 + i) * 2 + 0];
    ss += part[(g16 * 16 + i) * 2 + 1];
  }
  const float inv_cnt = 1.0f / (float)(CPG * LLEN);
  const float mu = s * inv_cnt;
  const float rsg = rsqrtf(ss * inv_cnt - mu * mu + GEPS);
  __shared__ float tile[32][68];
  const int t = threadIdx.x;
  const int cl = t >> 3, l8 = t & 7;
  const float aa = rsg * w[c0 + cl];
  const float dd = b[c0 + cl] - mu * aa;
  const float* xrow = x + ((size_t)n * CCH + c0 + cl) * LLEN + l0;
#pragma unroll
  for (int i = 0; i < 2; i++) {
    const int ll = (l8 + 8 * i) * 4;
    float4 v = *(const float4*)(xrow + ll);
    v.x = fmaf(v.x, aa, dd);
    v.y = fmaf(v.y, aa, dd);
    v.z = fmaf(v.z, aa, dd);
    v.w = fmaf(v.w, aa, dd);
    *(float4*)&tile[cl][ll] = v;
  }
  __syncthreads();
  const int l = t & 63, cg = t >> 6;      // each wave owns one 8-channel group
  const int labs = l0 + l;
  bf16x8 ov;
#pragma unroll
  for (int j = 0; j < 8; j++) ov[j] = (short)f2b(tile[cg * 8 + j][l]);
  const size_t pos = (((size_t)n * 256 + (labs >> 4)) * 8 + (c0 >> 5)) * 512 +
                     ((labs & 15) + 16 * cg) * 8;
  *(bf16x8*)(xn16 + pos) = ov;
}

// ------- QKV GEMM v2: block = 32 l-rows x 256 couts x 1 wsel (grid 256x3 =
//   768 blocks = 3/CU even). Wave owns 64 couts. Per kc: 6 loads / 8 MFMA
//   (768B/MFMA vs 1.25KB before); xn read 3x instead of 12x. -------
__global__ __launch_bounds__(256, 4) void qkv_mfma_kernel(
    const unsigned short* __restrict__ xn16,
    const unsigned short* __restrict__ w16,
    const float* __restrict__ bias_ws,
    unsigned short* __restrict__ q16,
    unsigned short* __restrict__ k16,
    unsigned short* __restrict__ v16) {
  const int t = threadIdx.x;
  const int lane = t & 63, wv = t >> 6;
  const int col = lane & 15, quad = lane >> 4;
  const int m0 = blockIdx.x * 32;            // 32 l-rows
  const int wsel = blockIdx.y;               // 0=q,1=k,2=v
  const int n = m0 >> 12;
  const int m16b = (m0 & 4095) >> 4;
  const int l0 = m0 & 4095;

  const unsigned short* xnb = xn16 + (((size_t)n * 256 + m16b) * 8) * 512 + lane * 8;
  const unsigned short* wb  = w16 + ((size_t)(wsel * 16 + wv * 4) * 8) * 512 + lane * 8;

  f32x4 acc[2][4];
#pragma unroll
  for (int mt = 0; mt < 2; mt++)
#pragma unroll
    for (int ct = 0; ct < 4; ct++) acc[mt][ct] = {0.f, 0.f, 0.f, 0.f};

  const int j = col & 7;
  if (wsel < 2) {
#pragma unroll
    for (int kc = 0; kc < 8; kc++) {
      bf16x8 xf[2], wf[4];
      xf[0] = *(const bf16x8*)(xnb + (size_t)kc * 512);
      xf[1] = *(const bf16x8*)(xnb + (size_t)(8 + kc) * 512);
#pragma unroll
      for (int ct = 0; ct < 4; ct++)
        wf[ct] = *(const bf16x8*)(wb + (size_t)(ct * 8 + kc) * 512);
#pragma unroll
      for (int mt = 0; mt < 2; mt++)
#pragma unroll
        for (int ct = 0; ct < 4; ct++)
          acc[mt][ct] = __builtin_amdgcn_mfma_f32_16x16x32_bf16(xf[mt], wf[ct], acc[mt][ct], 0, 0, 0);  // D[l][cout]
    }
    unsigned short* dst = (wsel == 0) ? q16 : k16;
#pragma unroll
    for (int ct = 0; ct < 4; ct++) {
      const float bias = bias_ws[wsel * CCH + wv * 64 + ct * 16 + col];
      const int lq = (ct & 1) * 2 + (col >> 3);
#pragma unroll
      for (int mt = 0; mt < 2; mt++) {
        const size_t base = (((size_t)n * 256 + m16b + mt) * 8 + wv * 2 + (ct >> 1)) * 512 + j;
#pragma unroll
        for (int r = 0; r < 4; r++)
          dst[base + ((quad * 4 + r) + 16 * lq) * 8] = f2b(acc[mt][ct][r] + bias);
      }
    }
  } else {
#pragma unroll
    for (int kc = 0; kc < 8; kc++) {
      bf16x8 xf[2], wf[4];
      xf[0] = *(const bf16x8*)(xnb + (size_t)kc * 512);
      xf[1] = *(const bf16x8*)(xnb + (size_t)(8 + kc) * 512);
#pragma unroll
      for (int ct = 0; ct < 4; ct++)
        wf[ct] = *(const bf16x8*)(wb + (size_t)(ct * 8 + kc) * 512);
#pragma unroll
      for (int mt = 0; mt < 2; mt++)
#pragma unroll
        for (int ct = 0; ct < 4; ct++)
          acc[mt][ct] = __builtin_amdgcn_mfma_f32_16x16x32_bf16(wf[ct], xf[mt], acc[mt][ct], 0, 0, 0);  // D[cout][l]
    }
#pragma unroll
    for (int ct = 0; ct < 4; ct++) {
      const size_t base = (((size_t)n * 128 + (l0 >> 5)) * 16 + wv * 4 + ct) * 512 + j;
#pragma unroll
      for (int mt = 0; mt < 2; mt++) {
        const int lq = mt * 2 + (col >> 3);
#pragma unroll
        for (int r = 0; r < 4; r++)
          v16[base + ((quad * 4 + r) + 16 * lq) * 8] =
              f2b(acc[mt][ct][r] + bias_ws[2 * CCH + wv * 64 + ct * 16 + quad * 4 + r]);
      }
    }
  }
}

// ------- Flash attention v7: qt=4, XCD swizzle, in-register P (permlane),
//   pointer-increment addressing (kp/vp advance by constant 16KB/chunk, all
//   frag loads at compile-time offsets -> address VALU ~gone), persistent
//   zero C-operand (no per-tile zero-init movs), peeled tail. -------
__global__ __launch_bounds__(256, 2) void attn_mfma_kernel(
    const unsigned short* __restrict__ q16,   // Q' tiled, pre-scaled
    const unsigned short* __restrict__ k16,   // K' tiled
    const unsigned short* __restrict__ v16,   // V' tiled
    unsigned short* __restrict__ o16) {       // O' tiled (normalized)
  __shared__ __align__(16) unsigned char shraw[20480];
  f32x4 (*red)[4][64] = (f32x4 (*)[4][64])shraw;                      // [srcwv][ct][lane] 16KB
  f32x4 (*lred)[64] = (f32x4 (*)[64])(shraw + 16384);                 // [srcwv][lane] 4KB
  const int t = threadIdx.x;
  const int lane = t & 63, wv = t >> 6;
  const int col = lane & 15, quad = lane >> 4;
  // Bijective XCD swizzle (512 blocks % 8 == 0): head = fid&7 -> one head
  // per XCD, its 1MB K/V resident in that XCD's private 4MB L2.
  const int fid = blockIdx.y * gridDim.x + blockIdx.x;
  const int nh = fid & 7, qx = fid >> 3;
  const int n = nh >> 2, h = nh & 3;
  const int hc = h * HD;
  const int qt0 = qx * 4;                     // base q16-tile (4 tiles = 64 rows)

  const unsigned short* qb = q16 + (size_t)n * (256 * 8 * 512);
  const unsigned short* kb = k16 + (size_t)n * (256 * 8 * 512);
  const unsigned short* vb = v16 + (size_t)n * (128 * 16 * 512);

  // Q B-frags (shared by all waves)
  bf16x8 bq[4][2];
#pragma unroll
  for (int qt = 0; qt < 4; qt++)
#pragma unroll
    for (int ks = 0; ks < 2; ks++)
      bq[qt][ks] = *(const bf16x8*)(qb + ((size_t)(qt0 + qt) * 8 + h * 2 + ks) * 512 + lane * 8);

  bf16x8 bones;
#pragma unroll
  for (int i = 0; i < 8; i++) bones[i] = (short)0x3F80;   // bf16 1.0
  const f32x4 zf = {0.f, 0.f, 0.f, 0.f};      // persistent zero C-operand

  f32x4 o[4][4], lacc[4];
#pragma unroll
  for (int qt = 0; qt < 4; qt++) {
    lacc[qt] = {0.f, 0.f, 0.f, 0.f};
#pragma unroll
    for (int ct = 0; ct < 4; ct++) o[qt][ct] = {0.f, 0.f, 0.f, 0.f};
  }

  // Wave-base pointers; advance by 8192 ushorts (16KB) per 32-key chunk.
  const unsigned short* kp = kb + ((size_t)(wv * 64) * 8 + h * 2) * 512 + lane * 8;
  const unsigned short* vp = vb + ((size_t)(wv * 32) * 16 + h * 4) * 512 + lane * 8;

  bf16x8 kA[2][2], kB[2][2], vA[4], vB[4];
  auto loadK = [&](bf16x8 (&kr)[2][2], const unsigned short* p) {
#pragma unroll
    for (int kt = 0; kt < 2; kt++)
#pragma unroll
      for (int ks = 0; ks < 2; ks++)
        kr[kt][ks] = *(const bf16x8*)(p + kt * 4096 + ks * 512);
  };
  auto loadV = [&](bf16x8 (&vv)[4], const unsigned short* p) {
#pragma unroll
    for (int ct = 0; ct < 4; ct++) vv[ct] = *(const bf16x8*)(p + ct * 512);
  };

  auto chunk = [&](bf16x8 (&kr)[2][2], bf16x8 (&vv)[4]) {
    // S^T = K·Q^T; p = 2^s packed to bf16; permlane exchange -> PV A-frags.
    bf16x8 pa[4];
#pragma unroll
    for (int qt = 0; qt < 4; qt++) {
      unsigned a0, a1, b0, b1;
      {
        f32x4 s = __builtin_amdgcn_mfma_f32_16x16x32_bf16(kr[0][0], bq[qt][0], zf, 0, 0, 0);
        s = __builtin_amdgcn_mfma_f32_16x16x32_bf16(kr[0][1], bq[qt][1], s, 0, 0, 0);
        a0 = pack2bf(exp2_(s[0]), exp2_(s[1]));
        a1 = pack2bf(exp2_(s[2]), exp2_(s[3]));
      }
      {
        f32x4 s = __builtin_amdgcn_mfma_f32_16x16x32_bf16(kr[1][0], bq[qt][0], zf, 0, 0, 0);
        s = __builtin_amdgcn_mfma_f32_16x16x32_bf16(kr[1][1], bq[qt][1], s, 0, 0, 0);
        b0 = pack2bf(exp2_(s[0]), exp2_(s[1]));
        b1 = pack2bf(exp2_(s[2]), exp2_(s[3]));
      }
      auto r0 = __builtin_amdgcn_permlane32_swap(a0, b0, false, false);
      auto s0 = __builtin_amdgcn_permlane16_swap(r0[0], r0[1], false, false);
      auto r1 = __builtin_amdgcn_permlane32_swap(a1, b1, false, false);
      auto s1 = __builtin_amdgcn_permlane16_swap(r1[0], r1[1], false, false);
      union { unsigned u[4]; bf16x8 v; } pu;
      pu.u[0] = s0[0];   // w0 = keys 8q'+0,1
      pu.u[1] = s1[0];   // w1 = keys 8q'+2,3
      pu.u[2] = s0[1];   // w2 = keys 8q'+4,5
      pu.u[3] = s1[1];   // w3 = keys 8q'+6,7
      pa[qt] = pu.v;
    }
    // PV + denominators — pure MFMA cluster
    __builtin_amdgcn_s_setprio(1);
#pragma unroll
    for (int qt = 0; qt < 4; qt++) {
      lacc[qt] = __builtin_amdgcn_mfma_f32_16x16x32_bf16(pa[qt], bones, lacc[qt], 0, 0, 0);
#pragma unroll
      for (int ct = 0; ct < 4; ct++)
        o[qt][ct] = __builtin_amdgcn_mfma_f32_16x16x32_bf16(pa[qt], vv[ct], o[qt][ct], 0, 0, 0);
    }
    __builtin_amdgcn_s_setprio(0);
  };

  loadK(kA, kp);
  loadV(vA, vp);
  for (int it = 0; it < 30; it += 2) {
    loadK(kB, kp + 8192);
    loadV(vB, vp + 8192);
    chunk(kA, vA);
    kp += 16384;
    vp += 16384;
    loadK(kA, kp);
    loadV(vA, vp);
    chunk(kB, vB);
  }
  loadK(kB, kp + 8192);
  loadV(vB, vp + 8192);
  chunk(kA, vA);
  chunk(kB, vB);

  // ---- merge across 4 waves, normalize, store O' tiled ----
  const int cch = hc + wv * 16 + col;        // channel this thread stores
  const int lquad16 = 16 * ((cch >> 3) & 3);
  const size_t ctile = cch >> 5;
#pragma unroll
  for (int qt = 0; qt < 4; qt++) {
    __syncthreads();
#pragma unroll
    for (int ct = 0; ct < 4; ct++) red[wv][ct][lane] = o[qt][ct];
    lred[wv][lane] = lacc[qt];
    __syncthreads();
    f32x4 os = red[0][wv][lane];
    os += red[1][wv][lane];
    os += red[2][wv][lane];
    os += red[3][wv][lane];
    f32x4 ls = lred[0][lane];
    ls += lred[1][lane];
    ls += lred[2][lane];
    ls += lred[3][lane];
    const size_t base = (((size_t)n * 256 + qt0 + qt) * 8 + ctile) * 512 + (cch & 7);
#pragma unroll
    for (int r = 0; r < 4; r++)
      o16[base + ((quad * 4 + r) + lquad16) * 8] = f2b(os[r] / ls[r]);
  }
}

// ------- Proj GEMM, 32-row M-tiles, register MFMA + bias + residual -> fp32 out -------
__global__ __launch_bounds__(256, 4) void proj_mfma_kernel(
    const unsigned short* __restrict__ o16,     // O' tiled
    const unsigned short* __restrict__ w16,     // tiled weights (pw at tile 48)
    const float* __restrict__ pbias,
    const float* __restrict__ x,
    float* __restrict__ out) {
  const int t = threadIdx.x;
  const int lane = t & 63, wv = t >> 6;
  const int col = lane & 15, quad = lane >> 4;
  const int m0 = blockIdx.x * 32;            // l rows
  const int by = blockIdx.y;
  const int co0 = by * 64;
  const int n = m0 >> 12, l0 = m0 & 4095;

  const unsigned short* ob = o16 + (size_t)n * (256 * 8 * 512);
  const unsigned short* wb = w16 + ((size_t)(48 + by * 4 + wv) * 8) * 512 + lane * 8;

  f32x4 acc[2];
#pragma unroll
  for (int i = 0; i < 2; i++) acc[i] = {0.f, 0.f, 0.f, 0.f};

#pragma unroll
  for (int kc = 0; kc < 8; kc++) {
    const bf16x8 aw = *(const bf16x8*)(wb + (size_t)kc * 512);
#pragma unroll
    for (int lt = 0; lt < 2; lt++) {
      const bf16x8 bo = *(const bf16x8*)(ob + ((size_t)((l0 >> 4) + lt) * 8 + kc) * 512 + lane * 8);
      acc[lt] = __builtin_amdgcn_mfma_f32_16x16x32_bf16(aw, bo, acc[lt], 0, 0, 0);  // D[cout][l]
    }
  }
#pragma unroll
  for (int lt = 0; lt < 2; lt++)
#pragma unroll
    for (int r = 0; r < 4; r++) {
      const int cout = co0 + wv * 16 + quad * 4 + r;
      const size_t idx = ((size_t)(n * CCH + cout)) * LLEN + l0 + lt * 16 + col;
      out[idx] = acc[lt][r] + pbias[cout] + x[idx];
    }
}

extern "C" void kernel_launch(void* const* d_in, const int* in_sizes, int n_in,
                              void* d_out, int out_size, void* d_ws, size_t ws_size,
                              hipStream_t stream) {
  (void)in_sizes; (void)n_in; (void)out_size; (void)ws_size;
  const float* x      = (const float*)d_in[0];
  const int*   mask   = (const int*)d_in[1];
  const float* norm_w = (const float*)d_in[2];
  const float* norm_b = (const float*)d_in[3];
  const float* q_w    = (const float*)d_in[4];
  const float* q_b    = (const float*)d_in[5];
  const float* k_w    = (const float*)d_in[6];
  const float* k_b    = (const float*)d_in[7];
  const float* v_w    = (const float*)d_in[8];
  const float* v_b    = (const float*)d_in[9];
  const float* p_w    = (const float*)d_in[10];
  const float* p_b    = (const float*)d_in[11];

  const size_t TSZ = (size_t)NBATCH * LLEN * CCH;   // 2097152 elements
  unsigned short* xn16 = (unsigned short*)d_ws;     // TSZ (tiled)
  unsigned short* q16  = xn16 + TSZ;                // tiled
  unsigned short* k16  = q16 + TSZ;                 // tiled
  unsigned short* v16  = k16 + TSZ;                 // tiled
  unsigned short* o16  = v16 + TSZ;                 // tiled
  unsigned short* w16  = o16 + TSZ;                 // 4*65536 (tiled)
  float* bias_ws = (float*)(w16 + 4 * 65536);       // 4*256
  float* part    = bias_ws + 1024;                  // 512
  // total ~21 MB

  float* out  = (float*)d_out;
  float* out2 = out + TSZ;   // mask chunk

  setup_kernel<<<544, 256, 0, stream>>>(q_w, k_w, v_w, p_w, q_b, k_b, v_b, p_b,
                                        x, mask, w16, bias_ws, part, out2);
  gn_apply_kernel<<<dim3(LLEN / 64, CCH / 32, NBATCH), 256, 0, stream>>>(
      x, norm_w, norm_b, part, xn16);
  qkv_mfma_kernel<<<dim3((NBATCH * LLEN) / 32, 3), 256, 0, stream>>>(
      xn16, w16, bias_ws, q16, k16, v16);
  attn_mfma_kernel<<<dim3(LLEN / 64, NBATCH * NHEAD), 256, 0, stream>>>(
      q16, k16, v16, o16);
  proj_mfma_kernel<<<dim3((NBATCH * LLEN) / 32, CCH / 64), 256, 0, stream>>>(
      o16, w16, bias_ws + 768, x, out);
}

// Round 4
// 142.260 us; speedup vs baseline: 1.0962x; 1.0333x over previous
//
#include <hip/hip_runtime.h>
#include <hip/hip_bf16.h>

// Problem constants (N=2, C=256, H=W=64) — float32 I/O per reference.
#define NBATCH 2
#define CCH    256
#define LLEN   4096      // H*W
#define NGROUP 8
#define CPG    32        // C / NGROUP
#define NHEAD  4
#define HD     64        // C / NHEAD
#define GEPS   1e-5f
// q pre-scale: hd^-0.5 * log2(e); scores feed v_exp_f32 (2^x) directly.
#define QSCALE 0.18033688011112042f

// Generic MFMA fragment tiling (for 16x16x32 bf16): a [R x 256ch] tensor is
// stored as tiles [r16][c32] of 512 ushorts; element (r, c) sits at
// tile*512 + ((r&15) + 16*((c>>3)&3))*8 + (c&7).

typedef short bf16x8 __attribute__((ext_vector_type(8)));
typedef float f32x4  __attribute__((ext_vector_type(4)));

__device__ __forceinline__ unsigned short f2b(float f) {
  unsigned u = __float_as_uint(f);
  u += 0x7FFFu + ((u >> 16) & 1u);
  return (unsigned short)(u >> 16);
}
// Native packed f32->bf16 convert (gfx950): 1 instr vs ~10 VALU for the
// header's software RNE path. Low half = first operand.
__device__ __forceinline__ unsigned cvtpk(float lo, float hi) {
  unsigned r;
  asm("v_cvt_pk_bf16_f32 %0, %1, %2" : "=v"(r) : "v"(lo), "v"(hi));
  return r;
}
__device__ __forceinline__ float exp2_(float x) {
#if __has_builtin(__builtin_amdgcn_exp2f)
  return __builtin_amdgcn_exp2f(x);
#else
  return exp2f(x);
#endif
}

// ------- setup: GN partial sums only (256 blocks, 16 per group) -------
__global__ __launch_bounds__(256) void setup_kernel(const float* __restrict__ x,
                                                    float* __restrict__ part) {
  __shared__ float rs[4], rss[4];
  const int sb = blockIdx.x;
  const int t = threadIdx.x;
  const int gidx = sb >> 4, sub = sb & 15;
  const float4* xp = (const float4*)(x + (size_t)gidx * (CPG * LLEN)) + (size_t)sub * 2048;
  float s = 0.f, ss = 0.f;
  for (int i = t; i < 2048; i += 256) {
    const float4 v = xp[i];
    s += v.x + v.y + v.z + v.w;
    ss = fmaf(v.x, v.x, ss);
    ss = fmaf(v.y, v.y, ss);
    ss = fmaf(v.z, v.z, ss);
    ss = fmaf(v.w, v.w, ss);
  }
#pragma unroll
  for (int off = 32; off; off >>= 1) {
    s  += __shfl_down(s, off);
    ss += __shfl_down(ss, off);
  }
  if ((t & 63) == 0) { rs[t >> 6] = s; rss[t >> 6] = ss; }
  __syncthreads();
  if (t == 0) {
    part[sb * 2 + 0] = rs[0] + rs[1] + rs[2] + rs[3];
    part[sb * 2 + 1] = rss[0] + rss[1] + rss[2] + rss[3];
  }
}

// ------- GN apply+transpose (blocks 0..1023) | weight tiling+bias
//   (1024..1279) | mask copy (1280..1311). Weight/mask parts have no
//   dependency on GN stats; w16/bias consumed first by qkv (later). -------
__global__ __launch_bounds__(256) void gn_apply_kernel(
    const float* __restrict__ x, const float* __restrict__ w,
    const float* __restrict__ b, const float* __restrict__ part,
    const float* __restrict__ qw, const float* __restrict__ kw,
    const float* __restrict__ vw, const float* __restrict__ pw,
    const float* __restrict__ qb, const float* __restrict__ kb,
    const float* __restrict__ vb, const float* __restrict__ pb,
    const int* __restrict__ mask,
    unsigned short* __restrict__ xn16, unsigned short* __restrict__ w16,
    float* __restrict__ bias_ws, float* __restrict__ out2) {
  __shared__ float tile[32][68];
  const int bx = blockIdx.x;
  const int t = threadIdx.x;
  if (bx < 1024) {
    const int lx = bx & 63, cy = (bx >> 6) & 7, n = bx >> 9;
    const int l0 = lx * 64, c0 = cy * 32;
    const int g16 = n * 8 + cy;
    float s = 0.f, ss = 0.f;
#pragma unroll
    for (int i = 0; i < 16; i++) {
      s  += part[(g16 * 16 + i) * 2 + 0];
      ss += part[(g16 * 16 + i) * 2 + 1];
    }
    const float inv_cnt = 1.0f / (float)(CPG * LLEN);
    const float mu = s * inv_cnt;
    const float rsg = rsqrtf(ss * inv_cnt - mu * mu + GEPS);
    const int cl = t >> 3, l8 = t & 7;
    const float aa = rsg * w[c0 + cl];
    const float dd = b[c0 + cl] - mu * aa;
    const float* xrow = x + ((size_t)n * CCH + c0 + cl) * LLEN + l0;
#pragma unroll
    for (int i = 0; i < 2; i++) {
      const int ll = (l8 + 8 * i) * 4;
      float4 v = *(const float4*)(xrow + ll);
      v.x = fmaf(v.x, aa, dd);
      v.y = fmaf(v.y, aa, dd);
      v.z = fmaf(v.z, aa, dd);
      v.w = fmaf(v.w, aa, dd);
      *(float4*)&tile[cl][ll] = v;
    }
    __syncthreads();
    const int l = t & 63, cg = t >> 6;    // each wave owns one 8-channel group
    const int labs = l0 + l;
    bf16x8 ov;
#pragma unroll
    for (int j = 0; j < 8; j++) ov[j] = (short)f2b(tile[cg * 8 + j][l]);
    const size_t pos = (((size_t)n * 256 + (labs >> 4)) * 8 + (c0 >> 5)) * 512 +
                       ((labs & 15) + 16 * cg) * 8;
    *(bf16x8*)(xn16 + pos) = ov;
  } else if (bx < 1280) {
    const int sb = bx - 1024;
    const int idx = sb * 256 + t;              // float4 units; 65536 total
    const int m = idx >> 14;                   // block-uniform
    const int rem = idx & 16383;
    const int cout = rem >> 6;                 // 0..255
    const int ch4 = (rem & 63) << 2;           // 0..252
    // no runtime-indexed pointer array (rule #20 scratch hazard)
    const float* srcp = (m == 0) ? qw : (m == 1) ? kw : (m == 2) ? vw : pw;
    const float sc = (m == 0) ? QSCALE : 1.0f;
    const float4 v = ((const float4*)srcp)[(size_t)cout * 64 + (ch4 >> 2)];
    unsigned short* dst = w16 +
        ((size_t)(m * 16 + (cout >> 4)) * 8 + (ch4 >> 5)) * 512 +
        ((cout & 15) + 16 * ((ch4 >> 3) & 3)) * 8 + (ch4 & 7);
    uint2 wd;
    wd.x = cvtpk(v.x * sc, v.y * sc);
    wd.y = cvtpk(v.z * sc, v.w * sc);
    *(uint2*)dst = wd;                         // 8B-aligned: ch4&7 in {0,4}
    if (sb == 0) {
      bias_ws[t]       = qb[t] * QSCALE;
      bias_ws[256 + t] = kb[t];
      bias_ws[512 + t] = vb[t];
      bias_ws[768 + t] = pb[t];
    }
  } else {
    const int i = (bx - 1280) * 256 + t;
    out2[i] = (float)mask[i];
  }
}

// ------- QKV GEMM v3: same loads as v2, but MFMA orientation chosen per
//   output so each lane's 4 acc values are 4 CONSECUTIVE ushorts in the
//   tiled layout: epilogue = 16 cvtpk + 8 uint2 stores (was 32 software
//   f2b + 32 scalar 2-byte stores). Layout bytes unchanged. -------
__global__ __launch_bounds__(256, 4) void qkv_mfma_kernel(
    const unsigned short* __restrict__ xn16,
    const unsigned short* __restrict__ w16,
    const float* __restrict__ bias_ws,
    unsigned short* __restrict__ q16,
    unsigned short* __restrict__ k16,
    unsigned short* __restrict__ v16) {
  const int t = threadIdx.x;
  const int lane = t & 63, wv = t >> 6;
  const int col = lane & 15, quad = lane >> 4;
  const int m0 = blockIdx.x * 32;            // 32 l-rows
  const int wsel = blockIdx.y;               // 0=q,1=k,2=v
  const int n = m0 >> 12;
  const int m16b = (m0 & 4095) >> 4;
  const int l0 = m0 & 4095;

  const unsigned short* xnb = xn16 + (((size_t)n * 256 + m16b) * 8) * 512 + lane * 8;
  const unsigned short* wb  = w16 + ((size_t)(wsel * 16 + wv * 4) * 8) * 512 + lane * 8;

  f32x4 acc[2][4];
#pragma unroll
  for (int mt = 0; mt < 2; mt++)
#pragma unroll
    for (int ct = 0; ct < 4; ct++) acc[mt][ct] = {0.f, 0.f, 0.f, 0.f};

#pragma unroll
  for (int kc = 0; kc < 8; kc++) {
    bf16x8 xf[2], wf[4];
    xf[0] = *(const bf16x8*)(xnb + (size_t)kc * 512);
    xf[1] = *(const bf16x8*)(xnb + (size_t)(8 + kc) * 512);
#pragma unroll
    for (int ct = 0; ct < 4; ct++)
      wf[ct] = *(const bf16x8*)(wb + (size_t)(ct * 8 + kc) * 512);
#pragma unroll
    for (int mt = 0; mt < 2; mt++)
#pragma unroll
      for (int ct = 0; ct < 4; ct++)
        acc[mt][ct] = (wsel < 2)
            ? __builtin_amdgcn_mfma_f32_16x16x32_bf16(wf[ct], xf[mt], acc[mt][ct], 0, 0, 0)   // D[cout][l]
            : __builtin_amdgcn_mfma_f32_16x16x32_bf16(xf[mt], wf[ct], acc[mt][ct], 0, 0, 0);  // D[key][vch]
  }

  if (wsel < 2) {
    // D[cout][l]: lane(col=l, quad), r -> cout = wv*64 + ct*16 + quad*4 + r.
    // Tiled q/k (rows=l, cols=ch): 4 consecutive ch per lane -> uint2 store.
    unsigned short* dst = (wsel == 0) ? q16 : k16;
#pragma unroll
    for (int ct = 0; ct < 4; ct++) {
      const float4 b4 = *(const float4*)&bias_ws[wsel * CCH + wv * 64 + ct * 16 + quad * 4];
#pragma unroll
      for (int mt = 0; mt < 2; mt++) {
        uint2 wd;
        wd.x = cvtpk(acc[mt][ct][0] + b4.x, acc[mt][ct][1] + b4.y);
        wd.y = cvtpk(acc[mt][ct][2] + b4.z, acc[mt][ct][3] + b4.w);
        *(uint2*)(dst + ((size_t)(n * 256 + m16b + mt) * 8 + wv * 2 + (ct >> 1)) * 512 +
                  (col + 16 * ((ct & 1) * 2 + (quad >> 1))) * 8 + (quad & 1) * 4) = wd;
      }
    }
  } else {
    // D[key][vch]: lane(col=vch, quad), r -> key = l0 + mt*16 + quad*4 + r.
    // Tiled V' (rows=vch, cols=key): 4 consecutive keys per lane -> uint2.
#pragma unroll
    for (int ct = 0; ct < 4; ct++) {
      const float bv = bias_ws[2 * CCH + wv * 64 + ct * 16 + col];
#pragma unroll
      for (int mt = 0; mt < 2; mt++) {
        uint2 wd;
        wd.x = cvtpk(acc[mt][ct][0] + bv, acc[mt][ct][1] + bv);
        wd.y = cvtpk(acc[mt][ct][2] + bv, acc[mt][ct][3] + bv);
        *(uint2*)(v16 + (((size_t)n * 128 + (l0 >> 5)) * 16 + wv * 4 + ct) * 512 +
                  (col + 16 * (mt * 2 + (quad >> 1))) * 8 + (quad & 1) * 4) = wd;
      }
    }
  }
}

// ------- Flash attention v8: qt=4, XCD swizzle, K/V reg ping-pong,
//   in-register P via NATIVE v_cvt_pk_bf16_f32 + permlane (the header's
//   software RNE pack was ~10 VALU/pack — the hidden VALUBusy). -------
__global__ __launch_bounds__(256, 2) void attn_mfma_kernel(
    const unsigned short* __restrict__ q16,   // Q' tiled, pre-scaled
    const unsigned short* __restrict__ k16,   // K' tiled
    const unsigned short* __restrict__ v16,   // V' tiled
    unsigned short* __restrict__ o16) {       // O' tiled (normalized)
  __shared__ __align__(16) unsigned char shraw[20480];
  f32x4 (*red)[4][64] = (f32x4 (*)[4][64])shraw;                      // [srcwv][ct][lane] 16KB
  f32x4 (*lred)[64] = (f32x4 (*)[64])(shraw + 16384);                 // [srcwv][lane] 4KB
  const int t = threadIdx.x;
  const int lane = t & 63, wv = t >> 6;
  const int col = lane & 15, quad = lane >> 4;
  // Bijective XCD swizzle (512 blocks % 8 == 0): head = fid&7 -> one head
  // per XCD, its 1MB K/V resident in that XCD's private 4MB L2.
  const int fid = blockIdx.y * gridDim.x + blockIdx.x;
  const int nh = fid & 7, qx = fid >> 3;
  const int n = nh >> 2, h = nh & 3;
  const int hc = h * HD;
  const int qt0 = qx * 4;                     // base q16-tile (4 tiles = 64 rows)

  const unsigned short* qb = q16 + (size_t)n * (256 * 8 * 512);
  const unsigned short* kb = k16 + (size_t)n * (256 * 8 * 512);
  const unsigned short* vb = v16 + (size_t)n * (128 * 16 * 512);

  // Q B-frags (shared by all waves)
  bf16x8 bq[4][2];
#pragma unroll
  for (int qt = 0; qt < 4; qt++)
#pragma unroll
    for (int ks = 0; ks < 2; ks++)
      bq[qt][ks] = *(const bf16x8*)(qb + ((size_t)(qt0 + qt) * 8 + h * 2 + ks) * 512 + lane * 8);

  bf16x8 bones;
#pragma unroll
  for (int i = 0; i < 8; i++) bones[i] = (short)0x3F80;   // bf16 1.0
  const f32x4 zf = {0.f, 0.f, 0.f, 0.f};      // persistent zero C-operand

  f32x4 o[4][4], lacc[4];
#pragma unroll
  for (int qt = 0; qt < 4; qt++) {
    lacc[qt] = {0.f, 0.f, 0.f, 0.f};
#pragma unroll
    for (int ct = 0; ct < 4; ct++) o[qt][ct] = {0.f, 0.f, 0.f, 0.f};
  }

  // Wave-base pointers; advance by 8192 ushorts (16KB) per 32-key chunk.
  const unsigned short* kp = kb + ((size_t)(wv * 64) * 8 + h * 2) * 512 + lane * 8;
  const unsigned short* vp = vb + ((size_t)(wv * 32) * 16 + h * 4) * 512 + lane * 8;

  bf16x8 kA[2][2], kB[2][2], vA[4], vB[4];
  auto loadK = [&](bf16x8 (&kr)[2][2], const unsigned short* p) {
#pragma unroll
    for (int kt = 0; kt < 2; kt++)
#pragma unroll
      for (int ks = 0; ks < 2; ks++)
        kr[kt][ks] = *(const bf16x8*)(p + kt * 4096 + ks * 512);
  };
  auto loadV = [&](bf16x8 (&vv)[4], const unsigned short* p) {
#pragma unroll
    for (int ct = 0; ct < 4; ct++) vv[ct] = *(const bf16x8*)(p + ct * 512);
  };

  auto chunk = [&](bf16x8 (&kr)[2][2], bf16x8 (&vv)[4]) {
    // S^T = K·Q^T; p = 2^s packed to bf16; permlane exchange -> PV A-frags.
    bf16x8 pa[4];
#pragma unroll
    for (int qt = 0; qt < 4; qt++) {
      unsigned a0, a1, b0, b1;
      {
        f32x4 s = __builtin_amdgcn_mfma_f32_16x16x32_bf16(kr[0][0], bq[qt][0], zf, 0, 0, 0);
        s = __builtin_amdgcn_mfma_f32_16x16x32_bf16(kr[0][1], bq[qt][1], s, 0, 0, 0);
        a0 = cvtpk(exp2_(s[0]), exp2_(s[1]));
        a1 = cvtpk(exp2_(s[2]), exp2_(s[3]));
      }
      {
        f32x4 s = __builtin_amdgcn_mfma_f32_16x16x32_bf16(kr[1][0], bq[qt][0], zf, 0, 0, 0);
        s = __builtin_amdgcn_mfma_f32_16x16x32_bf16(kr[1][1], bq[qt][1], s, 0, 0, 0);
        b0 = cvtpk(exp2_(s[0]), exp2_(s[1]));
        b1 = cvtpk(exp2_(s[2]), exp2_(s[3]));
      }
      auto r0 = __builtin_amdgcn_permlane32_swap(a0, b0, false, false);
      auto s0 = __builtin_amdgcn_permlane16_swap(r0[0], r0[1], false, false);
      auto r1 = __builtin_amdgcn_permlane32_swap(a1, b1, false, false);
      auto s1 = __builtin_amdgcn_permlane16_swap(r1[0], r1[1], false, false);
      union { unsigned u[4]; bf16x8 v; } pu;
      pu.u[0] = s0[0];   // w0 = keys 8q'+0,1
      pu.u[1] = s1[0];   // w1 = keys 8q'+2,3
      pu.u[2] = s0[1];   // w2 = keys 8q'+4,5
      pu.u[3] = s1[1];   // w3 = keys 8q'+6,7
      pa[qt] = pu.v;
    }
    // PV + denominators — pure MFMA cluster
    __builtin_amdgcn_s_setprio(1);
#pragma unroll
    for (int qt = 0; qt < 4; qt++) {
      lacc[qt] = __builtin_amdgcn_mfma_f32_16x16x32_bf16(pa[qt], bones, lacc[qt], 0, 0, 0);
#pragma unroll
      for (int ct = 0; ct < 4; ct++)
        o[qt][ct] = __builtin_amdgcn_mfma_f32_16x16x32_bf16(pa[qt], vv[ct], o[qt][ct], 0, 0, 0);
    }
    __builtin_amdgcn_s_setprio(0);
  };

  loadK(kA, kp);
  loadV(vA, vp);
  for (int it = 0; it < 30; it += 2) {
    loadK(kB, kp + 8192);
    loadV(vB, vp + 8192);
    chunk(kA, vA);
    kp += 16384;
    vp += 16384;
    loadK(kA, kp);
    loadV(vA, vp);
    chunk(kB, vB);
  }
  loadK(kB, kp + 8192);
  loadV(vB, vp + 8192);
  chunk(kA, vA);
  chunk(kB, vB);

  // ---- merge across 4 waves, normalize, store O' tiled ----
  const int cch = hc + wv * 16 + col;        // channel this thread stores
  const int lquad16 = 16 * ((cch >> 3) & 3);
  const size_t ctile = cch >> 5;
#pragma unroll
  for (int qt = 0; qt < 4; qt++) {
    __syncthreads();
#pragma unroll
    for (int ct = 0; ct < 4; ct++) red[wv][ct][lane] = o[qt][ct];
    lred[wv][lane] = lacc[qt];
    __syncthreads();
    f32x4 os = red[0][wv][lane];
    os += red[1][wv][lane];
    os += red[2][wv][lane];
    os += red[3][wv][lane];
    f32x4 ls = lred[0][lane];
    ls += lred[1][lane];
    ls += lred[2][lane];
    ls += lred[3][lane];
    const size_t base = (((size_t)n * 256 + qt0 + qt) * 8 + ctile) * 512 + (cch & 7);
#pragma unroll
    for (int r = 0; r < 4; r++)
      o16[base + ((quad * 4 + r) + lquad16) * 8] = f2b(os[r] / ls[r]);
  }
}

// ------- Proj GEMM, 32-row M-tiles, register MFMA + bias + residual -> fp32 out -------
__global__ __launch_bounds__(256, 4) void proj_mfma_kernel(
    const unsigned short* __restrict__ o16,     // O' tiled
    const unsigned short* __restrict__ w16,     // tiled weights (pw at tile 48)
    const float* __restrict__ pbias,
    const float* __restrict__ x,
    float* __restrict__ out) {
  const int t = threadIdx.x;
  const int lane = t & 63, wv = t >> 6;
  const int col = lane & 15, quad = lane >> 4;
  const int m0 = blockIdx.x * 32;            // l rows
  const int by = blockIdx.y;
  const int co0 = by * 64;
  const int n = m0 >> 12, l0 = m0 & 4095;

  const unsigned short* ob = o16 + (size_t)n * (256 * 8 * 512);
  const unsigned short* wb = w16 + ((size_t)(48 + by * 4 + wv) * 8) * 512 + lane * 8;

  f32x4 acc[2];
#pragma unroll
  for (int i = 0; i < 2; i++) acc[i] = {0.f, 0.f, 0.f, 0.f};

#pragma unroll
  for (int kc = 0; kc < 8; kc++) {
    const bf16x8 aw = *(const bf16x8*)(wb + (size_t)kc * 512);
#pragma unroll
    for (int lt = 0; lt < 2; lt++) {
      const bf16x8 bo = *(const bf16x8*)(ob + ((size_t)((l0 >> 4) + lt) * 8 + kc) * 512 + lane * 8);
      acc[lt] = __builtin_amdgcn_mfma_f32_16x16x32_bf16(aw, bo, acc[lt], 0, 0, 0);  // D[cout][l]
    }
  }
#pragma unroll
  for (int lt = 0; lt < 2; lt++)
#pragma unroll
    for (int r = 0; r < 4; r++) {
      const int cout = co0 + wv * 16 + quad * 4 + r;
      const size_t idx = ((size_t)(n * CCH + cout)) * LLEN + l0 + lt * 16 + col;
      out[idx] = acc[lt][r] + pbias[cout] + x[idx];
    }
}

extern "C" void kernel_launch(void* const* d_in, const int* in_sizes, int n_in,
                              void* d_out, int out_size, void* d_ws, size_t ws_size,
                              hipStream_t stream) {
  (void)in_sizes; (void)n_in; (void)out_size; (void)ws_size;
  const float* x      = (const float*)d_in[0];
  const int*   mask   = (const int*)d_in[1];
  const float* norm_w = (const float*)d_in[2];
  const float* norm_b = (const float*)d_in[3];
  const float* q_w    = (const float*)d_in[4];
  const float* q_b    = (const float*)d_in[5];
  const float* k_w    = (const float*)d_in[6];
  const float* k_b    = (const float*)d_in[7];
  const float* v_w    = (const float*)d_in[8];
  const float* v_b    = (const float*)d_in[9];
  const float* p_w    = (const float*)d_in[10];
  const float* p_b    = (const float*)d_in[11];

  const size_t TSZ = (size_t)NBATCH * LLEN * CCH;   // 2097152 elements
  unsigned short* xn16 = (unsigned short*)d_ws;     // TSZ (tiled)
  unsigned short* q16  = xn16 + TSZ;                // tiled
  unsigned short* k16  = q16 + TSZ;                 // tiled
  unsigned short* v16  = k16 + TSZ;                 // tiled
  unsigned short* o16  = v16 + TSZ;                 // tiled
  unsigned short* w16  = o16 + TSZ;                 // 4*65536 (tiled)
  float* bias_ws = (float*)(w16 + 4 * 65536);       // 4*256
  float* part    = bias_ws + 1024;                  // 512
  // total ~21 MB

  float* out  = (float*)d_out;
  float* out2 = out + TSZ;   // mask chunk

  setup_kernel<<<256, 256, 0, stream>>>(x, part);
  gn_apply_kernel<<<1312, 256, 0, stream>>>(
      x, norm_w, norm_b, part, q_w, k_w, v_w, p_w, q_b, k_b, v_b, p_b,
      mask, xn16, w16, bias_ws, out2);
  qkv_mfma_kernel<<<dim3((NBATCH * LLEN) / 32, 3), 256, 0, stream>>>(
      xn16, w16, bias_ws, q16, k16, v16);
  attn_mfma_kernel<<<dim3(LLEN / 64, NBATCH * NHEAD), 256, 0, stream>>>(
      q16, k16, v16, o16);
  proj_mfma_kernel<<<dim3((NBATCH * LLEN) / 32, CCH / 64), 256, 0, stream>>>(
      o16, w16, bias_ws + 768, x, out);
}